// Round 1
// baseline (405.539 us; speedup 1.0000x reference)
//
#include <hip/hip_runtime.h>
#include <stdint.h>

#define D_MODEL 1024
#define SEQ     2048
#define NHEAD   16
#define BATCH   2
#define NROWS   (BATCH*SEQ)   // 4096

typedef _Float16 f16;
typedef _Float16 f16x8 __attribute__((ext_vector_type(8)));
typedef _Float16 f16x4 __attribute__((ext_vector_type(4)));
typedef float    f32x4 __attribute__((ext_vector_type(4)));

__device__ __forceinline__ void gload16(const void* g, void* l) {
  __builtin_amdgcn_global_load_lds(
      (const __attribute__((address_space(1))) void*)g,
      (__attribute__((address_space(3))) void*)l, 16, 0, 0);
}

// ---------------- convert / split kernels ----------------
__global__ void split4_kernel(const float* __restrict__ in, f16* __restrict__ hi,
                              f16* __restrict__ lo, int n4) {
  int i = blockIdx.x * blockDim.x + threadIdx.x;
  if (i >= n4) return;
  float4 v = reinterpret_cast<const float4*>(in)[i];
  f16x4 h, l4;
  h[0] = (f16)v.x; h[1] = (f16)v.y; h[2] = (f16)v.z; h[3] = (f16)v.w;
  l4[0] = (f16)(v.x - (float)h[0]);
  l4[1] = (f16)(v.y - (float)h[1]);
  l4[2] = (f16)(v.z - (float)h[2]);
  l4[3] = (f16)(v.w - (float)h[3]);
  *reinterpret_cast<f16x4*>(hi + 4*(size_t)i) = h;
  *reinterpret_cast<f16x4*>(lo + 4*(size_t)i) = l4;
}

__global__ void cvt4_kernel(const float* __restrict__ in, f16* __restrict__ out, int n4) {
  int i = blockIdx.x * blockDim.x + threadIdx.x;
  if (i >= n4) return;
  float4 v = reinterpret_cast<const float4*>(in)[i];
  f16x4 h;
  h[0] = (f16)v.x; h[1] = (f16)v.y; h[2] = (f16)v.z; h[3] = (f16)v.w;
  *reinterpret_cast<f16x4*>(out + 4*(size_t)i) = h;
}

// ---------------- GEMM: C[M,N] = A[M,K] · B[N,K]^T  (NT) ----------------
// BM=128, BN=64, BK=32. 4 waves as 2x2; each wave computes 64x32.
// SPLIT_IN: acc += Ahi·Bhi + Ahi·Blo + Alo·Bhi  (fp16 hi/lo compensated product)
template<bool SPLIT_IN, bool SPLIT_OUT, bool F32_OUT>
__global__ __launch_bounds__(256, 2)
void gemm_nt(const f16* __restrict__ Ahi, const f16* __restrict__ Alo,
             const f16* __restrict__ Bhi, const f16* __restrict__ Blo,
             f16* __restrict__ Chi, f16* __restrict__ Clo, float* __restrict__ Cf,
             int M, int N, int K)
{
  __shared__ f16 sAhi[128*32];
  __shared__ f16 sAlo[128*32];
  __shared__ f16 sBhi[64*32];
  __shared__ f16 sBlo[64*32];

  const int tid = threadIdx.x;
  const int w = tid >> 6, l = tid & 63;
  const int wr = (w >> 1) * 64;   // wave row offset in tile
  const int wc = (w & 1) * 32;    // wave col offset in tile
  const int bm = blockIdx.y * 128, bn = blockIdx.x * 64;

  f32x4 acc[4][2] = {};

  const int srow = tid >> 2;            // staging row 0..63
  const int scol = (tid & 3) * 8;       // staging col (halves)

  for (int k0 = 0; k0 < K; k0 += 32) {
    __syncthreads();
    {
      const f16* ga = Ahi + (size_t)(bm + srow) * K + k0 + scol;
      gload16(ga,          (char*)sAhi + (w << 10));
      gload16(ga + 64*K,   (char*)sAhi + 4096 + (w << 10));
      const f16* gb = Bhi + (size_t)(bn + srow) * K + k0 + scol;
      gload16(gb,          (char*)sBhi + (w << 10));
      if (SPLIT_IN) {
        const f16* gal = Alo + (size_t)(bm + srow) * K + k0 + scol;
        gload16(gal,        (char*)sAlo + (w << 10));
        gload16(gal + 64*K, (char*)sAlo + 4096 + (w << 10));
        const f16* gbl = Blo + (size_t)(bn + srow) * K + k0 + scol;
        gload16(gbl,        (char*)sBlo + (w << 10));
      }
    }
    __syncthreads();

    const int ar = (l & 15);            // fragment row within 16
    const int ak = (l >> 4) * 16;       // fragment k byte offset
    f16x8 a_hi[4], a_lo[4];
#pragma unroll
    for (int mi = 0; mi < 4; mi++) {
      a_hi[mi] = *(const f16x8*)((const char*)sAhi + (size_t)(wr + mi*16 + ar) * 64 + ak);
      if (SPLIT_IN)
        a_lo[mi] = *(const f16x8*)((const char*)sAlo + (size_t)(wr + mi*16 + ar) * 64 + ak);
    }
#pragma unroll
    for (int ni = 0; ni < 2; ni++) {
      f16x8 b_hi = *(const f16x8*)((const char*)sBhi + (size_t)(wc + ni*16 + ar) * 64 + ak);
      f16x8 b_lo = {};
      if (SPLIT_IN)
        b_lo = *(const f16x8*)((const char*)sBlo + (size_t)(wc + ni*16 + ar) * 64 + ak);
#pragma unroll
      for (int mi = 0; mi < 4; mi++) {
        acc[mi][ni] = __builtin_amdgcn_mfma_f32_16x16x32_f16(a_hi[mi], b_hi, acc[mi][ni], 0, 0, 0);
        if (SPLIT_IN) {
          acc[mi][ni] = __builtin_amdgcn_mfma_f32_16x16x32_f16(a_hi[mi], b_lo, acc[mi][ni], 0, 0, 0);
          acc[mi][ni] = __builtin_amdgcn_mfma_f32_16x16x32_f16(a_lo[mi], b_hi, acc[mi][ni], 0, 0, 0);
        }
      }
    }
  }

  // epilogue: D row=(l>>4)*4+j, col=l&15
  const int crow0 = bm + wr + (l >> 4) * 4;
  const int ccol0 = bn + wc + (l & 15);
#pragma unroll
  for (int mi = 0; mi < 4; mi++) {
#pragma unroll
    for (int ni = 0; ni < 2; ni++) {
#pragma unroll
      for (int j = 0; j < 4; j++) {
        size_t idx = (size_t)(crow0 + mi*16 + j) * N + (ccol0 + ni*16);
        float v = acc[mi][ni][j];
        if (F32_OUT) {
          Cf[idx] = v;
        } else {
          f16 h = (f16)v;
          Chi[idx] = h;
          if (SPLIT_OUT) Clo[idx] = (f16)(v - (float)h);
        }
      }
    }
  }
}

// ---------------- flash attention (causal) ----------------
// grid: (SEQ/64, BATCH*NHEAD), 256 threads = 4 waves, each wave owns 16 q rows.
// QK^T via fp16 hi/lo split (3 MFMAs), PV plain fp16. KV tile = 32.
__global__ __launch_bounds__(256, 2)
void attn_kernel(const f16* __restrict__ Qhi, const f16* __restrict__ Qlo,
                 const f16* __restrict__ Khi, const f16* __restrict__ Klo,
                 const f16* __restrict__ V, f16* __restrict__ Out)
{
  __shared__ f16 sVt[64*32];      // V^T tile: [d_local 64][kv_local 32]
  __shared__ f16 sP[4*16*32];     // per-wave P tile [16 q][32 kv]

  const int tid = threadIdx.x, w = tid >> 6, l = tid & 63;
  const int bh = blockIdx.y, b = bh >> 4, h = bh & 15;
  const int q0 = blockIdx.x * 64;
  const int qw = q0 + w * 16;
  const size_t hoff = (size_t)h * 64;

  // Q fragments (persistent)
  f16x8 qhi[2], qlo[2];
  {
    const size_t base = (size_t)(b*SEQ + qw + (l & 15)) * D_MODEL + hoff + (l >> 4) * 8;
    qhi[0] = *(const f16x8*)(Qhi + base);
    qhi[1] = *(const f16x8*)(Qhi + base + 32);
    qlo[0] = *(const f16x8*)(Qlo + base);
    qlo[1] = *(const f16x8*)(Qlo + base + 32);
  }

  f32x4 o[4] = {};
  float m_run[4], l_run[4];
#pragma unroll
  for (int j = 0; j < 4; j++) { m_run[j] = -INFINITY; l_run[j] = 0.f; }

  const int kvend = q0 + 64;   // causal bound (<= SEQ)
  for (int kv0 = 0; kv0 < kvend; kv0 += 32) {
    __syncthreads();
    // stage V^T tile
    {
      const int r = tid >> 3, c0 = (tid & 7) * 8;
      f16x8 v8 = *(const f16x8*)(V + (size_t)(b*SEQ + kv0 + r) * D_MODEL + hoff + c0);
#pragma unroll
      for (int jj = 0; jj < 8; jj++) sVt[(c0 + jj) * 32 + r] = v8[jj];
    }
    __syncthreads();

    // S = Q K^T (split fp16: 3 MFMAs per fragment pair)
    f32x4 s[2] = {};
#pragma unroll
    for (int ks = 0; ks < 2; ks++) {
#pragma unroll
      for (int ni = 0; ni < 2; ni++) {
        const size_t kb = (size_t)(b*SEQ + kv0 + ni*16 + (l & 15)) * D_MODEL + hoff + ks*32 + (l >> 4) * 8;
        f16x8 khi = *(const f16x8*)(Khi + kb);
        f16x8 klo = *(const f16x8*)(Klo + kb);
        s[ni] = __builtin_amdgcn_mfma_f32_16x16x32_f16(qhi[ks], khi, s[ni], 0, 0, 0);
        s[ni] = __builtin_amdgcn_mfma_f32_16x16x32_f16(qhi[ks], klo, s[ni], 0, 0, 0);
        s[ni] = __builtin_amdgcn_mfma_f32_16x16x32_f16(qlo[ks], khi, s[ni], 0, 0, 0);
      }
    }

    // scale + causal mask + row max
    float pv[2][4], pm[4];
#pragma unroll
    for (int j = 0; j < 4; j++) {
      const int q_abs = qw + (l >> 4) * 4 + j;
      pm[j] = -INFINITY;
#pragma unroll
      for (int ni = 0; ni < 2; ni++) {
        const int kv_abs = kv0 + ni*16 + (l & 15);
        float vv = s[ni][j] * 0.125f;
        if (kv_abs > q_abs) vv = -INFINITY;
        pv[ni][j] = vv;
        pm[j] = fmaxf(pm[j], vv);
      }
    }
#pragma unroll
    for (int mk = 1; mk < 16; mk <<= 1)
#pragma unroll
      for (int j = 0; j < 4; j++) pm[j] = fmaxf(pm[j], __shfl_xor(pm[j], mk));

    // online softmax update
    float sc[4], ps[4];
#pragma unroll
    for (int j = 0; j < 4; j++) {
      const float mn = fmaxf(m_run[j], pm[j]);
      sc[j] = __expf(m_run[j] - mn);     // first tile: exp(-inf)=0
      m_run[j] = mn;
      const float p0 = __expf(pv[0][j] - mn);
      const float p1 = __expf(pv[1][j] - mn);
      pv[0][j] = p0; pv[1][j] = p1;
      ps[j] = p0 + p1;
    }
#pragma unroll
    for (int mk = 1; mk < 16; mk <<= 1)
#pragma unroll
      for (int j = 0; j < 4; j++) ps[j] += __shfl_xor(ps[j], mk);
#pragma unroll
    for (int j = 0; j < 4; j++) l_run[j] = l_run[j] * sc[j] + ps[j];
#pragma unroll
    for (int nd = 0; nd < 4; nd++)
#pragma unroll
      for (int j = 0; j < 4; j++) o[nd][j] *= sc[j];

    // P -> LDS (per-wave region), then PV
#pragma unroll
    for (int ni = 0; ni < 2; ni++)
#pragma unroll
      for (int j = 0; j < 4; j++)
        sP[w*512 + ((l >> 4) * 4 + j) * 32 + ni*16 + (l & 15)] = (f16)pv[ni][j];

    f16x8 pa = *(const f16x8*)((const char*)sP + (w << 10) + (l & 15) * 64 + (l >> 4) * 16);
#pragma unroll
    for (int nd = 0; nd < 4; nd++) {
      f16x8 bv = *(const f16x8*)((const char*)sVt + (size_t)(nd*16 + (l & 15)) * 64 + (l >> 4) * 16);
      o[nd] = __builtin_amdgcn_mfma_f32_16x16x32_f16(pa, bv, o[nd], 0, 0, 0);
    }
  }

  // epilogue
#pragma unroll
  for (int j = 0; j < 4; j++) {
    const float inv = 1.0f / l_run[j];
    const size_t row = (size_t)(b*SEQ + qw + (l >> 4) * 4 + j) * D_MODEL + hoff + (l & 15);
#pragma unroll
    for (int nd = 0; nd < 4; nd++)
      Out[row + nd*16] = (f16)(o[nd][j] * inv);
  }
}

// ---------------- launcher ----------------
extern "C" void kernel_launch(void* const* d_in, const int* in_sizes, int n_in,
                              void* d_out, int out_size, void* d_ws, size_t ws_size,
                              hipStream_t stream) {
  const float* x  = (const float*)d_in[0];
  const float* pq = (const float*)d_in[1];
  const float* pk = (const float*)d_in[2];
  const float* pv = (const float*)d_in[3];
  const float* po = (const float*)d_in[4];
  float* out = (float*)d_out;

  char* ws = (char*)d_ws;
  size_t off = 0;
  auto alloc = [&](size_t elems) {
    f16* p = (f16*)(ws + off);
    off += ((elems * 2 + 255) & ~(size_t)255);
    return p;
  };
  f16* x_hi  = alloc((size_t)NROWS * D_MODEL);
  f16* x_lo  = alloc((size_t)NROWS * D_MODEL);
  f16* wq_hi = alloc((size_t)D_MODEL * D_MODEL);
  f16* wq_lo = alloc((size_t)D_MODEL * D_MODEL);
  f16* wk_hi = alloc((size_t)D_MODEL * D_MODEL);
  f16* wk_lo = alloc((size_t)D_MODEL * D_MODEL);
  f16* wv_h  = alloc((size_t)D_MODEL * D_MODEL);
  f16* wo_h  = alloc((size_t)D_MODEL * D_MODEL);
  f16* q_hi  = alloc((size_t)NROWS * D_MODEL);
  f16* q_lo  = alloc((size_t)NROWS * D_MODEL);
  f16* k_hi  = alloc((size_t)NROWS * D_MODEL);
  f16* k_lo  = alloc((size_t)NROWS * D_MODEL);
  f16* v_h   = alloc((size_t)NROWS * D_MODEL);
  f16* ao    = alloc((size_t)NROWS * D_MODEL);

  const int n4x = NROWS * D_MODEL / 4;     // 1048576
  const int n4w = D_MODEL * D_MODEL / 4;   // 262144
  split4_kernel<<<n4x/256, 256, 0, stream>>>(x,  x_hi,  x_lo,  n4x);
  split4_kernel<<<n4w/256, 256, 0, stream>>>(pq, wq_hi, wq_lo, n4w);
  split4_kernel<<<n4w/256, 256, 0, stream>>>(pk, wk_hi, wk_lo, n4w);
  cvt4_kernel  <<<n4w/256, 256, 0, stream>>>(pv, wv_h, n4w);
  cvt4_kernel  <<<n4w/256, 256, 0, stream>>>(po, wo_h, n4w);

  dim3 gg(D_MODEL/64, NROWS/128);  // (16, 32)
  gemm_nt<true,  true,  false><<<gg, 256, 0, stream>>>(x_hi, x_lo, wq_hi, wq_lo, q_hi, q_lo, nullptr, NROWS, D_MODEL, D_MODEL);
  gemm_nt<true,  true,  false><<<gg, 256, 0, stream>>>(x_hi, x_lo, wk_hi, wk_lo, k_hi, k_lo, nullptr, NROWS, D_MODEL, D_MODEL);
  gemm_nt<false, false, false><<<gg, 256, 0, stream>>>(x_hi, nullptr, wv_h, nullptr, v_h, nullptr, nullptr, NROWS, D_MODEL, D_MODEL);

  attn_kernel<<<dim3(SEQ/64, BATCH*NHEAD), 256, 0, stream>>>(q_hi, q_lo, k_hi, k_lo, v_h, ao);

  gemm_nt<false, false, true><<<gg, 256, 0, stream>>>(ao, nullptr, wo_h, nullptr, nullptr, nullptr, out, NROWS, D_MODEL, D_MODEL);
}

// Round 2
// 342.612 us; speedup vs baseline: 1.1837x; 1.1837x over previous
//
#include <hip/hip_runtime.h>
#include <stdint.h>

#define D_MODEL 1024
#define SEQ     2048
#define NHEAD   16
#define BATCH   2
#define NROWS   (BATCH*SEQ)   // 4096

typedef _Float16 f16;
typedef _Float16 f16x8 __attribute__((ext_vector_type(8)));
typedef _Float16 f16x4 __attribute__((ext_vector_type(4)));
typedef float    f32x4 __attribute__((ext_vector_type(4)));

__device__ __forceinline__ void gload16(const void* g, void* l) {
  __builtin_amdgcn_global_load_lds(
      (const __attribute__((address_space(1))) void*)g,
      (__attribute__((address_space(3))) void*)l, 16, 0, 0);
}

// ---------------- convert / split kernels ----------------
__global__ void split4_kernel(const float* __restrict__ in, f16* __restrict__ hi,
                              f16* __restrict__ lo, int n4) {
  int i = blockIdx.x * blockDim.x + threadIdx.x;
  if (i >= n4) return;
  float4 v = reinterpret_cast<const float4*>(in)[i];
  f16x4 h, l4;
  h[0] = (f16)v.x; h[1] = (f16)v.y; h[2] = (f16)v.z; h[3] = (f16)v.w;
  l4[0] = (f16)(v.x - (float)h[0]);
  l4[1] = (f16)(v.y - (float)h[1]);
  l4[2] = (f16)(v.z - (float)h[2]);
  l4[3] = (f16)(v.w - (float)h[3]);
  *reinterpret_cast<f16x4*>(hi + 4*(size_t)i) = h;
  *reinterpret_cast<f16x4*>(lo + 4*(size_t)i) = l4;
}

__global__ void cvt4_kernel(const float* __restrict__ in, f16* __restrict__ out, int n4) {
  int i = blockIdx.x * blockDim.x + threadIdx.x;
  if (i >= n4) return;
  float4 v = reinterpret_cast<const float4*>(in)[i];
  f16x4 h;
  h[0] = (f16)v.x; h[1] = (f16)v.y; h[2] = (f16)v.z; h[3] = (f16)v.w;
  *reinterpret_cast<f16x4*>(out + 4*(size_t)i) = h;
}

// ---------------- GEMM: C[M,N] = A[M,K] · B[N,K]^T  (NT) ----------------
// BM=128, BN=64, BK=32. 4 waves as 2x2; each wave computes 64x32.
template<bool SPLIT_IN, bool SPLIT_OUT, bool F32_OUT>
__global__ __launch_bounds__(256, 2)
void gemm_nt(const f16* __restrict__ Ahi, const f16* __restrict__ Alo,
             const f16* __restrict__ Bhi, const f16* __restrict__ Blo,
             f16* __restrict__ Chi, f16* __restrict__ Clo, float* __restrict__ Cf,
             int M, int N, int K)
{
  __shared__ f16 sAhi[128*32];
  __shared__ f16 sAlo[128*32];
  __shared__ f16 sBhi[64*32];
  __shared__ f16 sBlo[64*32];

  const int tid = threadIdx.x;
  const int w = tid >> 6, l = tid & 63;
  const int wr = (w >> 1) * 64;
  const int wc = (w & 1) * 32;
  const int bm = blockIdx.y * 128, bn = blockIdx.x * 64;

  f32x4 acc[4][2] = {};

  const int srow = tid >> 2;
  const int scol = (tid & 3) * 8;

  for (int k0 = 0; k0 < K; k0 += 32) {
    __syncthreads();
    {
      const f16* ga = Ahi + (size_t)(bm + srow) * K + k0 + scol;
      gload16(ga,          (char*)sAhi + (w << 10));
      gload16(ga + 64*K,   (char*)sAhi + 4096 + (w << 10));
      const f16* gb = Bhi + (size_t)(bn + srow) * K + k0 + scol;
      gload16(gb,          (char*)sBhi + (w << 10));
      if (SPLIT_IN) {
        const f16* gal = Alo + (size_t)(bm + srow) * K + k0 + scol;
        gload16(gal,        (char*)sAlo + (w << 10));
        gload16(gal + 64*K, (char*)sAlo + 4096 + (w << 10));
        const f16* gbl = Blo + (size_t)(bn + srow) * K + k0 + scol;
        gload16(gbl,        (char*)sBlo + (w << 10));
      }
    }
    __syncthreads();

    const int ar = (l & 15);
    const int ak = (l >> 4) * 16;
    f16x8 a_hi[4], a_lo[4];
#pragma unroll
    for (int mi = 0; mi < 4; mi++) {
      a_hi[mi] = *(const f16x8*)((const char*)sAhi + (size_t)(wr + mi*16 + ar) * 64 + ak);
      if (SPLIT_IN)
        a_lo[mi] = *(const f16x8*)((const char*)sAlo + (size_t)(wr + mi*16 + ar) * 64 + ak);
    }
#pragma unroll
    for (int ni = 0; ni < 2; ni++) {
      f16x8 b_hi = *(const f16x8*)((const char*)sBhi + (size_t)(wc + ni*16 + ar) * 64 + ak);
      f16x8 b_lo = {};
      if (SPLIT_IN)
        b_lo = *(const f16x8*)((const char*)sBlo + (size_t)(wc + ni*16 + ar) * 64 + ak);
#pragma unroll
      for (int mi = 0; mi < 4; mi++) {
        acc[mi][ni] = __builtin_amdgcn_mfma_f32_16x16x32_f16(a_hi[mi], b_hi, acc[mi][ni], 0, 0, 0);
        if (SPLIT_IN) {
          acc[mi][ni] = __builtin_amdgcn_mfma_f32_16x16x32_f16(a_hi[mi], b_lo, acc[mi][ni], 0, 0, 0);
          acc[mi][ni] = __builtin_amdgcn_mfma_f32_16x16x32_f16(a_lo[mi], b_hi, acc[mi][ni], 0, 0, 0);
        }
      }
    }
  }

  const int crow0 = bm + wr + (l >> 4) * 4;
  const int ccol0 = bn + wc + (l & 15);
#pragma unroll
  for (int mi = 0; mi < 4; mi++) {
#pragma unroll
    for (int ni = 0; ni < 2; ni++) {
#pragma unroll
      for (int j = 0; j < 4; j++) {
        size_t idx = (size_t)(crow0 + mi*16 + j) * N + (ccol0 + ni*16);
        float v = acc[mi][ni][j];
        if (F32_OUT) {
          Cf[idx] = v;
        } else {
          f16 h = (f16)v;
          Chi[idx] = h;
          if (SPLIT_OUT) Clo[idx] = (f16)(v - (float)h);
        }
      }
    }
  }
}

// ---------------- flash attention v2 (causal) ----------------
// QBLK=128 (4 waves x 32 q rows), KVBLK=64.
// K(hi/lo) + VT staged to LDS via global_load_lds with source-side XOR
// pre-swizzle (chunk c of row r holds global chunk c^(r&7)); all ds_read_b128
// fragment reads apply the same XOR -> balanced banks.
// VT is V pre-transposed in global: VT[m][b*SEQ+s].
__global__ __launch_bounds__(256, 3)
void attn_kernel(const f16* __restrict__ Qhi, const f16* __restrict__ Qlo,
                 const f16* __restrict__ Khi, const f16* __restrict__ Klo,
                 const f16* __restrict__ VT, f16* __restrict__ Out)
{
  __shared__ f16 sKhi[64*64];
  __shared__ f16 sKlo[64*64];
  __shared__ f16 sVT [64*64];
  __shared__ f16 sP  [4*32*64];   // per-wave 32x64, XOR-swizzled

  const int tid = threadIdx.x, w = tid >> 6, l = tid & 63;
  // XCD-bijective swizzle: 512 blocks, 8 XCDs, 64 consecutive wg per XCD
  // -> each XCD works on 4 consecutive bh (its K/V stays in its L2).
  const int flat = blockIdx.y * 16 + blockIdx.x;
  const int wg = (flat & 7) * 64 + (flat >> 3);
  const int qx = wg & 15;
  const int bh = wg >> 4;
  const int b = bh >> 4, h = bh & 15;
  const int q0 = qx * 128;
  const int qw = q0 + w * 32;
  const size_t hoff = (size_t)h * 64;

  // persistent Q fragments: [qi(16-row sub)][ks]
  f16x8 qh[2][2], ql[2][2];
#pragma unroll
  for (int qi = 0; qi < 2; qi++)
#pragma unroll
    for (int ks = 0; ks < 2; ks++) {
      const size_t base = (size_t)(b*SEQ + qw + qi*16 + (l & 15)) * D_MODEL
                        + hoff + ks*32 + (l >> 4) * 8;
      qh[qi][ks] = *(const f16x8*)(Qhi + base);
      ql[qi][ks] = *(const f16x8*)(Qlo + base);
    }

  f32x4 o[2][4] = {};
  float m_run[2][4], l_run[2][4];
#pragma unroll
  for (int qi = 0; qi < 2; qi++)
#pragma unroll
    for (int j = 0; j < 4; j++) { m_run[qi][j] = -INFINITY; l_run[qi][j] = 0.f; }

  // staging geometry: each wave stages 8 rows per call, 2 calls per 64-row tile
  const int srow8 = l >> 3;                 // row within wave's 8-row group
  const int schunk = (l & 7) ^ (l >> 3);    // pre-swizzled source 16B-chunk

  const int kvend = q0 + 128;
  for (int kv0 = 0; kv0 < kvend; kv0 += 64) {
    __syncthreads();
    {
      const f16* kh = Khi + ((size_t)(b*SEQ + kv0)) * D_MODEL + hoff;
      const f16* kl2 = Klo + ((size_t)(b*SEQ + kv0)) * D_MODEL + hoff;
#pragma unroll
      for (int c = 0; c < 2; c++) {
        const int r = c*32 + w*8 + srow8;               // 0..63 tile-local
        const int ldsb = (c*32 + w*8) * 128;            // wave-uniform
        gload16(kh  + (size_t)r * D_MODEL + 8*schunk, (char*)sKhi + ldsb);
        gload16(kl2 + (size_t)r * D_MODEL + 8*schunk, (char*)sKlo + ldsb);
        gload16(VT + (hoff + r) * (size_t)NROWS + (size_t)(b*SEQ + kv0) + 8*schunk,
                (char*)sVT + ldsb);
      }
    }
    __syncthreads();

    if (kv0 <= qw + 31) {   // wave has at least one unmasked row in this tile
      // ---- S = Q K^T (split fp16) ----
      f32x4 s[2][4] = {};
#pragma unroll
      for (int ni = 0; ni < 4; ni++) {
        const int row = ni*16 + (l & 15);
        const int key = l & 7;
#pragma unroll
        for (int ks = 0; ks < 2; ks++) {
          const int boff = row*128 + 16*((ks*4 + (l >> 4)) ^ key);
          f16x8 bh_ = *(const f16x8*)((const char*)sKhi + boff);
          f16x8 bl_ = *(const f16x8*)((const char*)sKlo + boff);
#pragma unroll
          for (int qi = 0; qi < 2; qi++) {
            s[qi][ni] = __builtin_amdgcn_mfma_f32_16x16x32_f16(qh[qi][ks], bh_, s[qi][ni], 0, 0, 0);
            s[qi][ni] = __builtin_amdgcn_mfma_f32_16x16x32_f16(qh[qi][ks], bl_, s[qi][ni], 0, 0, 0);
            s[qi][ni] = __builtin_amdgcn_mfma_f32_16x16x32_f16(ql[qi][ks], bh_, s[qi][ni], 0, 0, 0);
          }
        }
      }

      // ---- scale + causal mask + row max ----
      const bool need_mask = (kv0 + 63) > qw;
      float p[2][4][4], pm[2][4];
#pragma unroll
      for (int qi = 0; qi < 2; qi++)
#pragma unroll
        for (int j = 0; j < 4; j++) {
          pm[qi][j] = -INFINITY;
#pragma unroll
          for (int ni = 0; ni < 4; ni++) {
            float vv = s[qi][ni][j] * 0.125f;
            if (need_mask) {
              const int kv_abs = kv0 + ni*16 + (l & 15);
              const int q_abs  = qw + qi*16 + (l >> 4) * 4 + j;
              if (kv_abs > q_abs) vv = -INFINITY;
            }
            p[qi][ni][j] = vv;
            pm[qi][j] = fmaxf(pm[qi][j], vv);
          }
        }
#pragma unroll
      for (int mk = 1; mk < 16; mk <<= 1)
#pragma unroll
        for (int qi = 0; qi < 2; qi++)
#pragma unroll
          for (int j = 0; j < 4; j++) pm[qi][j] = fmaxf(pm[qi][j], __shfl_xor(pm[qi][j], mk));

      // ---- online softmax ----
      float sc[2][4], ps[2][4];
#pragma unroll
      for (int qi = 0; qi < 2; qi++)
#pragma unroll
        for (int j = 0; j < 4; j++) {
          const float mn = fmaxf(m_run[qi][j], pm[qi][j]);
          sc[qi][j] = __expf(m_run[qi][j] - mn);
          m_run[qi][j] = mn;
          float acc = 0.f;
#pragma unroll
          for (int ni = 0; ni < 4; ni++) {
            const float pe = __expf(p[qi][ni][j] - mn);
            p[qi][ni][j] = pe;
            acc += pe;
          }
          ps[qi][j] = acc;
        }
#pragma unroll
      for (int mk = 1; mk < 16; mk <<= 1)
#pragma unroll
        for (int qi = 0; qi < 2; qi++)
#pragma unroll
          for (int j = 0; j < 4; j++) ps[qi][j] += __shfl_xor(ps[qi][j], mk);
#pragma unroll
      for (int qi = 0; qi < 2; qi++)
#pragma unroll
        for (int j = 0; j < 4; j++) l_run[qi][j] = l_run[qi][j] * sc[qi][j] + ps[qi][j];
#pragma unroll
      for (int qi = 0; qi < 2; qi++)
#pragma unroll
        for (int nd = 0; nd < 4; nd++)
#pragma unroll
          for (int j = 0; j < 4; j++) o[qi][nd][j] *= sc[qi][j];

      // ---- P -> LDS (swizzled), then PV ----
#pragma unroll
      for (int qi = 0; qi < 2; qi++)
#pragma unroll
        for (int ni = 0; ni < 4; ni++)
#pragma unroll
          for (int j = 0; j < 4; j++) {
            const int qr = qi*16 + (l >> 4) * 4 + j;
            const int kv = ni*16 + (l & 15);
            int byte = qr*128 + kv*2;
            byte ^= (qr & 7) << 4;
            *(f16*)((char*)sP + (w << 12) + byte) = (f16)p[qi][ni][j];
          }

#pragma unroll
      for (int ks = 0; ks < 2; ks++) {
        f16x8 pa[2];
#pragma unroll
        for (int qi = 0; qi < 2; qi++) {
          const int qr = qi*16 + (l & 15);
          const int boff = qr*128 + 16*((ks*4 + (l >> 4)) ^ (qr & 7));
          pa[qi] = *(const f16x8*)((const char*)sP + (w << 12) + boff);
        }
#pragma unroll
        for (int nd = 0; nd < 4; nd++) {
          const int d = nd*16 + (l & 15);
          const int boff = d*128 + 16*((ks*4 + (l >> 4)) ^ (d & 7));
          f16x8 bv = *(const f16x8*)((const char*)sVT + boff);
#pragma unroll
          for (int qi = 0; qi < 2; qi++)
            o[qi][nd] = __builtin_amdgcn_mfma_f32_16x16x32_f16(pa[qi], bv, o[qi][nd], 0, 0, 0);
        }
      }
    }
  }

  // ---- epilogue ----
#pragma unroll
  for (int qi = 0; qi < 2; qi++)
#pragma unroll
    for (int j = 0; j < 4; j++) {
      const float inv = 1.0f / l_run[qi][j];
      const size_t row = (size_t)(b*SEQ + qw + qi*16 + (l >> 4) * 4 + j) * D_MODEL
                       + hoff + (l & 15);
#pragma unroll
      for (int nd = 0; nd < 4; nd++)
        Out[row + nd*16] = (f16)(o[qi][nd][j] * inv);
    }
}

// ---------------- launcher ----------------
extern "C" void kernel_launch(void* const* d_in, const int* in_sizes, int n_in,
                              void* d_out, int out_size, void* d_ws, size_t ws_size,
                              hipStream_t stream) {
  const float* x  = (const float*)d_in[0];
  const float* pq = (const float*)d_in[1];
  const float* pk = (const float*)d_in[2];
  const float* pv = (const float*)d_in[3];
  const float* po = (const float*)d_in[4];
  float* out = (float*)d_out;

  char* ws = (char*)d_ws;
  size_t off = 0;
  auto alloc = [&](size_t elems) {
    f16* p = (f16*)(ws + off);
    off += ((elems * 2 + 255) & ~(size_t)255);
    return p;
  };
  f16* x_hi  = alloc((size_t)NROWS * D_MODEL);
  f16* x_lo  = alloc((size_t)NROWS * D_MODEL);
  f16* wq_hi = alloc((size_t)D_MODEL * D_MODEL);
  f16* wq_lo = alloc((size_t)D_MODEL * D_MODEL);
  f16* wk_hi = alloc((size_t)D_MODEL * D_MODEL);
  f16* wk_lo = alloc((size_t)D_MODEL * D_MODEL);
  f16* wv_h  = alloc((size_t)D_MODEL * D_MODEL);
  f16* wo_h  = alloc((size_t)D_MODEL * D_MODEL);
  f16* q_hi  = alloc((size_t)NROWS * D_MODEL);
  f16* q_lo  = alloc((size_t)NROWS * D_MODEL);
  f16* k_hi  = alloc((size_t)NROWS * D_MODEL);
  f16* k_lo  = alloc((size_t)NROWS * D_MODEL);
  f16* vt    = alloc((size_t)NROWS * D_MODEL);   // VT[m][b*SEQ+s]
  f16* ao    = alloc((size_t)NROWS * D_MODEL);

  const int n4x = NROWS * D_MODEL / 4;
  const int n4w = D_MODEL * D_MODEL / 4;
  split4_kernel<<<n4x/256, 256, 0, stream>>>(x,  x_hi,  x_lo,  n4x);
  split4_kernel<<<n4w/256, 256, 0, stream>>>(pq, wq_hi, wq_lo, n4w);
  split4_kernel<<<n4w/256, 256, 0, stream>>>(pk, wk_hi, wk_lo, n4w);
  cvt4_kernel  <<<n4w/256, 256, 0, stream>>>(pv, wv_h, n4w);
  cvt4_kernel  <<<n4w/256, 256, 0, stream>>>(po, wo_h, n4w);

  dim3 gg(D_MODEL/64, NROWS/128);  // (16, 32)
  gemm_nt<true,  true,  false><<<gg, 256, 0, stream>>>(x_hi, x_lo, wq_hi, wq_lo, q_hi, q_lo, nullptr, NROWS, D_MODEL, D_MODEL);
  gemm_nt<true,  true,  false><<<gg, 256, 0, stream>>>(x_hi, x_lo, wk_hi, wk_lo, k_hi, k_lo, nullptr, NROWS, D_MODEL, D_MODEL);
  // V projection, transposed output for free: VT[m][n] = sum_k wv[m][k] x[n][k]
  dim3 gv(NROWS/64, D_MODEL/128);  // (64, 8)
  gemm_nt<false, false, false><<<gv, 256, 0, stream>>>(wv_h, nullptr, x_hi, nullptr, vt, nullptr, nullptr, D_MODEL, NROWS, D_MODEL);

  attn_kernel<<<dim3(16, 32), 256, 0, stream>>>(q_hi, q_lo, k_hi, k_lo, vt, ao);

  gemm_nt<false, false, true><<<gg, 256, 0, stream>>>(ao, nullptr, wo_h, nullptr, nullptr, nullptr, out, NROWS, D_MODEL, D_MODEL);
}

// Round 3
// 251.086 us; speedup vs baseline: 1.6151x; 1.3645x over previous
//
#include <hip/hip_runtime.h>
#include <stdint.h>

#define D_MODEL 1024
#define SEQ     2048
#define NHEAD   16
#define BATCH   2
#define NROWS   (BATCH*SEQ)   // 4096

typedef _Float16 f16;
typedef _Float16 f16x8 __attribute__((ext_vector_type(8)));
typedef _Float16 f16x4 __attribute__((ext_vector_type(4)));
typedef float    f32x4 __attribute__((ext_vector_type(4)));

#define MFMA16 __builtin_amdgcn_mfma_f32_16x16x32_f16

__device__ __forceinline__ void gload16(const void* g, void* l) {
  __builtin_amdgcn_global_load_lds(
      (const __attribute__((address_space(1))) void*)g,
      (__attribute__((address_space(3))) void*)l, 16, 0, 0);
}

// ---------------- convert / split kernels ----------------
__global__ void split4_kernel(const float* __restrict__ in, f16* __restrict__ hi,
                              f16* __restrict__ lo, int n4, float scale) {
  int i = blockIdx.x * blockDim.x + threadIdx.x;
  if (i >= n4) return;
  float4 v = reinterpret_cast<const float4*>(in)[i];
  v.x *= scale; v.y *= scale; v.z *= scale; v.w *= scale;
  f16x4 h, l4;
  h[0] = (f16)v.x; h[1] = (f16)v.y; h[2] = (f16)v.z; h[3] = (f16)v.w;
  l4[0] = (f16)(v.x - (float)h[0]);
  l4[1] = (f16)(v.y - (float)h[1]);
  l4[2] = (f16)(v.z - (float)h[2]);
  l4[3] = (f16)(v.w - (float)h[3]);
  *reinterpret_cast<f16x4*>(hi + 4*(size_t)i) = h;
  *reinterpret_cast<f16x4*>(lo + 4*(size_t)i) = l4;
}

__global__ void cvt4_kernel(const float* __restrict__ in, f16* __restrict__ out, int n4) {
  int i = blockIdx.x * blockDim.x + threadIdx.x;
  if (i >= n4) return;
  float4 v = reinterpret_cast<const float4*>(in)[i];
  f16x4 h;
  h[0] = (f16)v.x; h[1] = (f16)v.y; h[2] = (f16)v.z; h[3] = (f16)v.w;
  *reinterpret_cast<f16x4*>(out + 4*(size_t)i) = h;
}

// ---------------- GEMM: C[M,N] = A[M,K] · B[N,K]^T  (NT) ----------------
template<bool SPLIT_IN, bool SPLIT_OUT, bool F32_OUT>
__global__ __launch_bounds__(256, 2)
void gemm_nt(const f16* __restrict__ Ahi, const f16* __restrict__ Alo,
             const f16* __restrict__ Bhi, const f16* __restrict__ Blo,
             f16* __restrict__ Chi, f16* __restrict__ Clo, float* __restrict__ Cf,
             int M, int N, int K)
{
  __shared__ f16 sAhi[128*32];
  __shared__ f16 sAlo[128*32];
  __shared__ f16 sBhi[64*32];
  __shared__ f16 sBlo[64*32];

  const int tid = threadIdx.x;
  const int w = tid >> 6, l = tid & 63;
  const int wr = (w >> 1) * 64;
  const int wc = (w & 1) * 32;
  const int bm = blockIdx.y * 128, bn = blockIdx.x * 64;

  f32x4 acc[4][2] = {};

  const int srow = tid >> 2;
  const int scol = (tid & 3) * 8;

  for (int k0 = 0; k0 < K; k0 += 32) {
    __syncthreads();
    {
      const f16* ga = Ahi + (size_t)(bm + srow) * K + k0 + scol;
      gload16(ga,          (char*)sAhi + (w << 10));
      gload16(ga + 64*K,   (char*)sAhi + 4096 + (w << 10));
      const f16* gb = Bhi + (size_t)(bn + srow) * K + k0 + scol;
      gload16(gb,          (char*)sBhi + (w << 10));
      if (SPLIT_IN) {
        const f16* gal = Alo + (size_t)(bm + srow) * K + k0 + scol;
        gload16(gal,        (char*)sAlo + (w << 10));
        gload16(gal + 64*K, (char*)sAlo + 4096 + (w << 10));
        const f16* gbl = Blo + (size_t)(bn + srow) * K + k0 + scol;
        gload16(gbl,        (char*)sBlo + (w << 10));
      }
    }
    __syncthreads();

    const int ar = (l & 15);
    const int ak = (l >> 4) * 16;
    f16x8 a_hi[4], a_lo[4];
#pragma unroll
    for (int mi = 0; mi < 4; mi++) {
      a_hi[mi] = *(const f16x8*)((const char*)sAhi + (size_t)(wr + mi*16 + ar) * 64 + ak);
      if (SPLIT_IN)
        a_lo[mi] = *(const f16x8*)((const char*)sAlo + (size_t)(wr + mi*16 + ar) * 64 + ak);
    }
#pragma unroll
    for (int ni = 0; ni < 2; ni++) {
      f16x8 b_hi = *(const f16x8*)((const char*)sBhi + (size_t)(wc + ni*16 + ar) * 64 + ak);
      f16x8 b_lo = {};
      if (SPLIT_IN)
        b_lo = *(const f16x8*)((const char*)sBlo + (size_t)(wc + ni*16 + ar) * 64 + ak);
#pragma unroll
      for (int mi = 0; mi < 4; mi++) {
        acc[mi][ni] = MFMA16(a_hi[mi], b_hi, acc[mi][ni], 0, 0, 0);
        if (SPLIT_IN) {
          acc[mi][ni] = MFMA16(a_hi[mi], b_lo, acc[mi][ni], 0, 0, 0);
          acc[mi][ni] = MFMA16(a_lo[mi], b_hi, acc[mi][ni], 0, 0, 0);
        }
      }
    }
  }

  const int crow0 = bm + wr + (l >> 4) * 4;
  const int ccol0 = bn + wc + (l & 15);
#pragma unroll
  for (int mi = 0; mi < 4; mi++) {
#pragma unroll
    for (int ni = 0; ni < 2; ni++) {
#pragma unroll
      for (int j = 0; j < 4; j++) {
        size_t idx = (size_t)(crow0 + mi*16 + j) * N + (ccol0 + ni*16);
        float v = acc[mi][ni][j];
        if (F32_OUT) {
          Cf[idx] = v;
        } else {
          f16 h = (f16)v;
          Chi[idx] = h;
          if (SPLIT_OUT) Clo[idx] = (f16)(v - (float)h);
        }
      }
    }
  }
}

// ---------------- flash attention v3 (causal) ----------------
// QBLK=64 (4 waves x 16 q rows), KVBLK=32, double-buffered K/V staging with
// counted vmcnt(3) (T3/T4 2-deep pipeline). Q pre-scaled by 0.125*log2(e) at
// weight split -> softmax in exp2 domain. Causal-balanced block mapping:
// each CU's 4 resident blocks get qx pairs {c, 31-c} (constant per-CU work);
// each XCD keeps 4 heads' K/V L2-resident.
// LDS per buffer (12KB): sKhi[32x64] | sKlo[32x64] | sVT[64 d][32 kv];
// sP: 4 waves x [16][32]. All tiles XOR-swizzled (source-side pre-swizzle).
__global__ __launch_bounds__(256, 4)
void attn_kernel(const f16* __restrict__ Qhi, const f16* __restrict__ Qlo,
                 const f16* __restrict__ Khi, const f16* __restrict__ Klo,
                 const f16* __restrict__ VT, f16* __restrict__ Out)
{
  __shared__ __align__(16) char smem[28672];   // 2*12288 + 4096

  const int tid = threadIdx.x, w = tid >> 6, l = tid & 63;
  const int flat = blockIdx.x;
  const int xcd = flat & 7, slot = flat >> 3;
  const int r4 = slot >> 5, ii = slot & 31;
  const int bh = xcd * 4 + r4;                 // XCD keeps 4 heads resident
  const int qx = (r4 & 1) ? (31 - ii) : ii;    // per-CU qx pairing {c,31-c}
  const int b = bh >> 4, h = bh & 15;
  const int q0 = qx * 64;
  const int qw = q0 + w * 16;
  const int bS = b * SEQ;
  const size_t hoff = (size_t)h * 64;
  const int niter = 2 * qx + 2;

  // persistent Q fragments (pre-scaled by 0.125*log2e via weight split)
  f16x8 qh[2], ql[2];
#pragma unroll
  for (int ks = 0; ks < 2; ks++) {
    const size_t base = (size_t)(bS + qw + (l & 15)) * D_MODEL + hoff + ks * 32 + (l >> 4) * 8;
    qh[ks] = *(const f16x8*)(Qhi + base);
    ql[ks] = *(const f16x8*)(Qlo + base);
  }

  f32x4 o[4] = {};
  float m_run[4], l_run[4];
#pragma unroll
  for (int j = 0; j < 4; j++) { m_run[j] = -INFINITY; l_run[j] = 0.f; }

  const int k_src_off = 8 * ((l & 7) ^ (l >> 3));
  const int v_src_off = 8 * ((l & 3) ^ ((l >> 3) & 3));

  auto stage = [&](int t) {
    char* dst = smem + (t & 1) * 12288;
    const int kv0 = t * 32;
    const size_t krow = (size_t)(bS + kv0 + w * 8 + (l >> 3)) * D_MODEL + hoff + k_src_off;
    gload16(Khi + krow, dst + w * 1024);
    gload16(Klo + krow, dst + 4096 + w * 1024);
    const size_t vrow = (hoff + w * 16 + (l >> 2)) * (size_t)NROWS + bS + kv0 + v_src_off;
    gload16(VT + vrow, dst + 8192 + w * 1024);
  };

  stage(0);

  for (int t = 0; t < niter; t++) {
    if (t + 1 < niter) {
      stage(t + 1);                                  // issue next tile first
      asm volatile("s_waitcnt vmcnt(3)" ::: "memory");  // drain current only
    } else {
      asm volatile("s_waitcnt vmcnt(0)" ::: "memory");
    }
    __builtin_amdgcn_s_barrier();

    const int kv0 = t * 32;
    if (kv0 <= qw + 15) {
      const char* bufK = smem + (t & 1) * 12288;

      // ---- S = Q K^T (split fp16, exp2 domain) ----
      f32x4 s[2] = {};
#pragma unroll
      for (int ni = 0; ni < 2; ni++) {
        const int row = ni * 16 + (l & 15);
#pragma unroll
        for (int ks = 0; ks < 2; ks++) {
          const int boff = row * 128 + 16 * ((ks * 4 + (l >> 4)) ^ (row & 7));
          f16x8 kh8 = *(const f16x8*)(bufK + boff);
          f16x8 kl8 = *(const f16x8*)(bufK + 4096 + boff);
          s[ni] = MFMA16(qh[ks], kh8, s[ni], 0, 0, 0);
          s[ni] = MFMA16(qh[ks], kl8, s[ni], 0, 0, 0);
          s[ni] = MFMA16(ql[ks], kh8, s[ni], 0, 0, 0);
        }
      }

      // ---- causal mask + row max ----
      const bool need_mask = (kv0 + 31) > qw;
      float p0[4], p1[4], pm[4];
#pragma unroll
      for (int j = 0; j < 4; j++) {
        float a = s[0][j], c = s[1][j];
        if (need_mask) {
          const int q_abs = qw + (l >> 4) * 4 + j;
          if (kv0 + (l & 15) > q_abs)      a = -INFINITY;
          if (kv0 + 16 + (l & 15) > q_abs) c = -INFINITY;
        }
        p0[j] = a; p1[j] = c;
        pm[j] = fmaxf(a, c);
      }
#pragma unroll
      for (int mk = 1; mk < 16; mk <<= 1)
#pragma unroll
        for (int j = 0; j < 4; j++) pm[j] = fmaxf(pm[j], __shfl_xor(pm[j], mk));

      // ---- online softmax (exp2) ----
      float sc[4], ps[4];
#pragma unroll
      for (int j = 0; j < 4; j++) {
        const float mn = fmaxf(m_run[j], pm[j]);
        sc[j] = __builtin_amdgcn_exp2f(m_run[j] - mn);
        m_run[j] = mn;
        const float e0 = __builtin_amdgcn_exp2f(p0[j] - mn);
        const float e1 = __builtin_amdgcn_exp2f(p1[j] - mn);
        p0[j] = e0; p1[j] = e1;
        ps[j] = e0 + e1;
      }
#pragma unroll
      for (int mk = 1; mk < 16; mk <<= 1)
#pragma unroll
        for (int j = 0; j < 4; j++) ps[j] += __shfl_xor(ps[j], mk);
#pragma unroll
      for (int j = 0; j < 4; j++) l_run[j] = l_run[j] * sc[j] + ps[j];
#pragma unroll
      for (int nd = 0; nd < 4; nd++)
#pragma unroll
        for (int j = 0; j < 4; j++) o[nd][j] *= sc[j];

      // ---- P -> LDS (swizzled, per-wave region), then PV ----
      char* pbase = smem + 24576 + w * 1024;
#pragma unroll
      for (int j = 0; j < 4; j++) {
        const int prow = (l >> 4) * 4 + j;
        const int key = (prow >> 1) & 3;
        const int c0 = (l & 15);
        {
          const int byte = prow * 64 + 16 * ((c0 >> 3) ^ key) + (c0 & 7) * 2;
          *(f16*)(pbase + byte) = (f16)p0[j];
        }
        {
          const int col = 16 + c0;
          const int byte = prow * 64 + 16 * ((col >> 3) ^ key) + (col & 7) * 2;
          *(f16*)(pbase + byte) = (f16)p1[j];
        }
      }
      const int pr = l & 15;
      f16x8 pa = *(const f16x8*)(pbase + pr * 64 + 16 * ((l >> 4) ^ ((pr >> 1) & 3)));
#pragma unroll
      for (int nd = 0; nd < 4; nd++) {
        const int d = nd * 16 + (l & 15);
        f16x8 bv = *(const f16x8*)(bufK + 8192 + d * 64 + 16 * ((l >> 4) ^ ((d >> 1) & 3)));
        o[nd] = MFMA16(pa, bv, o[nd], 0, 0, 0);
      }
    }
    __builtin_amdgcn_s_barrier();
  }

  // ---- epilogue ----
#pragma unroll
  for (int j = 0; j < 4; j++) {
    const float inv = 1.0f / l_run[j];
    const size_t row = (size_t)(bS + qw + (l >> 4) * 4 + j) * D_MODEL + hoff + (l & 15);
#pragma unroll
    for (int nd = 0; nd < 4; nd++)
      Out[row + nd*16] = (f16)(o[nd][j] * inv);
  }
}

// ---------------- launcher ----------------
extern "C" void kernel_launch(void* const* d_in, const int* in_sizes, int n_in,
                              void* d_out, int out_size, void* d_ws, size_t ws_size,
                              hipStream_t stream) {
  const float* x  = (const float*)d_in[0];
  const float* pq = (const float*)d_in[1];
  const float* pk = (const float*)d_in[2];
  const float* pv = (const float*)d_in[3];
  const float* po = (const float*)d_in[4];
  float* out = (float*)d_out;

  char* ws = (char*)d_ws;
  size_t off = 0;
  auto alloc = [&](size_t elems) {
    f16* p = (f16*)(ws + off);
    off += ((elems * 2 + 255) & ~(size_t)255);
    return p;
  };
  f16* x_hi  = alloc((size_t)NROWS * D_MODEL);
  f16* x_lo  = alloc((size_t)NROWS * D_MODEL);
  f16* wq_hi = alloc((size_t)D_MODEL * D_MODEL);
  f16* wq_lo = alloc((size_t)D_MODEL * D_MODEL);
  f16* wk_hi = alloc((size_t)D_MODEL * D_MODEL);
  f16* wk_lo = alloc((size_t)D_MODEL * D_MODEL);
  f16* wv_h  = alloc((size_t)D_MODEL * D_MODEL);
  f16* wo_h  = alloc((size_t)D_MODEL * D_MODEL);
  f16* q_hi  = alloc((size_t)NROWS * D_MODEL);
  f16* q_lo  = alloc((size_t)NROWS * D_MODEL);
  f16* k_hi  = alloc((size_t)NROWS * D_MODEL);
  f16* k_lo  = alloc((size_t)NROWS * D_MODEL);
  f16* vt    = alloc((size_t)NROWS * D_MODEL);   // VT[m][b*SEQ+s]
  f16* ao    = alloc((size_t)NROWS * D_MODEL);

  const int n4x = NROWS * D_MODEL / 4;
  const int n4w = D_MODEL * D_MODEL / 4;
  // Fold softmax scale (1/8) and log2(e) into Wq -> logits in exp2 domain.
  const float qscale = 0.125f * 1.44269504088896f;
  split4_kernel<<<n4x/256, 256, 0, stream>>>(x,  x_hi,  x_lo,  n4x, 1.0f);
  split4_kernel<<<n4w/256, 256, 0, stream>>>(pq, wq_hi, wq_lo, n4w, qscale);
  split4_kernel<<<n4w/256, 256, 0, stream>>>(pk, wk_hi, wk_lo, n4w, 1.0f);
  cvt4_kernel  <<<n4w/256, 256, 0, stream>>>(pv, wv_h, n4w);
  cvt4_kernel  <<<n4w/256, 256, 0, stream>>>(po, wo_h, n4w);

  dim3 gg(D_MODEL/64, NROWS/128);  // (16, 32)
  gemm_nt<true,  true,  false><<<gg, 256, 0, stream>>>(x_hi, x_lo, wq_hi, wq_lo, q_hi, q_lo, nullptr, NROWS, D_MODEL, D_MODEL);
  gemm_nt<true,  true,  false><<<gg, 256, 0, stream>>>(x_hi, x_lo, wk_hi, wk_lo, k_hi, k_lo, nullptr, NROWS, D_MODEL, D_MODEL);
  // V projection with transposed output: VT[m][n] = sum_k wv[m][k] x[n][k]
  dim3 gv(NROWS/64, D_MODEL/128);  // (64, 8)
  gemm_nt<false, false, false><<<gv, 256, 0, stream>>>(wv_h, nullptr, x_hi, nullptr, vt, nullptr, nullptr, D_MODEL, NROWS, D_MODEL);

  attn_kernel<<<dim3(1024), 256, 0, stream>>>(q_hi, q_lo, k_hi, k_lo, vt, ao);

  gemm_nt<false, false, true><<<gg, 256, 0, stream>>>(ao, nullptr, wo_h, nullptr, nullptr, nullptr, out, NROWS, D_MODEL, D_MODEL);
}

// Round 5
// 196.093 us; speedup vs baseline: 2.0681x; 1.2804x over previous
//
#include <hip/hip_runtime.h>
#include <stdint.h>

#define D_MODEL 1024
#define SEQ     2048
#define NHEAD   16
#define BATCH   2
#define NROWS   (BATCH*SEQ)   // 4096

typedef _Float16 f16;
typedef _Float16 f16x8 __attribute__((ext_vector_type(8)));
typedef _Float16 f16x4 __attribute__((ext_vector_type(4)));
typedef __fp16   h16x2 __attribute__((ext_vector_type(2)));
typedef float    f32x4 __attribute__((ext_vector_type(4)));

#define MFMA16 __builtin_amdgcn_mfma_f32_16x16x32_f16

__device__ __forceinline__ void gload16(const void* g, void* l) {
  __builtin_amdgcn_global_load_lds(
      (const __attribute__((address_space(1))) void*)g,
      (__attribute__((address_space(3))) void*)l, 16, 0, 0);
}

__device__ __forceinline__ int pkh2(float a, float b) {
  union { h16x2 h; int i; } u;
  u.h = __builtin_amdgcn_cvt_pkrtz(a, b);
  return u.i;
}

// ---------------- convert / split kernels ----------------
__global__ void split4_kernel(const float* __restrict__ in, f16* __restrict__ hi,
                              f16* __restrict__ lo, int n4, float scale) {
  int i = blockIdx.x * blockDim.x + threadIdx.x;
  if (i >= n4) return;
  float4 v = reinterpret_cast<const float4*>(in)[i];
  v.x *= scale; v.y *= scale; v.z *= scale; v.w *= scale;
  f16x4 h, l4;
  h[0] = (f16)v.x; h[1] = (f16)v.y; h[2] = (f16)v.z; h[3] = (f16)v.w;
  l4[0] = (f16)(v.x - (float)h[0]);
  l4[1] = (f16)(v.y - (float)h[1]);
  l4[2] = (f16)(v.z - (float)h[2]);
  l4[3] = (f16)(v.w - (float)h[3]);
  *reinterpret_cast<f16x4*>(hi + 4*(size_t)i) = h;
  *reinterpret_cast<f16x4*>(lo + 4*(size_t)i) = l4;
}

__global__ void cvt4_kernel(const float* __restrict__ in, f16* __restrict__ out, int n4) {
  int i = blockIdx.x * blockDim.x + threadIdx.x;
  if (i >= n4) return;
  float4 v = reinterpret_cast<const float4*>(in)[i];
  f16x4 h;
  h[0] = (f16)v.x; h[1] = (f16)v.y; h[2] = (f16)v.z; h[3] = (f16)v.w;
  *reinterpret_cast<f16x4*>(out + 4*(size_t)i) = h;
}

// ---------------- GEMM: C[M,N] = A[M,K] · B[N,K]^T  (NT) ----------------
// BM=128, BN=64, BK=32, double-buffered staging with counted vmcnt.
// COLCHUNK: XCD-chunk along bx (for V gemm where B is the big matrix).
template<bool SPLIT_IN, bool SPLIT_OUT, bool F32_OUT, bool COLCHUNK>
__global__ __launch_bounds__(256, 2)
void gemm_nt(const f16* __restrict__ Ahi, const f16* __restrict__ Alo,
             const f16* __restrict__ Bhi, const f16* __restrict__ Blo,
             f16* __restrict__ Chi, f16* __restrict__ Clo, float* __restrict__ Cf,
             int M, int N, int K)
{
  constexpr int ALO_OFF = 8192;
  constexpr int B_OFF   = SPLIT_IN ? 16384 : 8192;
  constexpr int BLO_OFF = 20480;
  constexpr int STRIDE  = SPLIT_IN ? 24576 : 12288;
  __shared__ __align__(16) char smem[2 * STRIDE];

  const int tid = threadIdx.x;
  const int w = tid >> 6, l = tid & 63;
  const int wr = (w >> 1) * 64;
  const int wc = (w & 1) * 32;

  // XCD-chunked bijective block swizzle (nwg % 8 == 0 for all our launches)
  const int gx = gridDim.x, gy = gridDim.y;
  const int nwg = gx * gy;
  const int flat = blockIdx.y * gx + blockIdx.x;
  const int swz = (flat & 7) * (nwg >> 3) + (flat >> 3);
  const int bxn = COLCHUNK ? (swz / gy) : (swz % gx);
  const int byn = COLCHUNK ? (swz % gy) : (swz / gx);
  const int bm = byn * 128, bn = bxn * 64;

  f32x4 acc[4][2] = {};

  const int srow = tid >> 2;
  const int scol = (tid & 3) * 8;

  auto stage = [&](int kt) {
    char* dst = smem + (kt & 1) * STRIDE;
    const int k0 = kt * 32;
    const f16* ga = Ahi + (size_t)(bm + srow) * K + k0 + scol;
    gload16(ga,        dst + (w << 10));
    gload16(ga + 64*K, dst + 4096 + (w << 10));
    const f16* gb = Bhi + (size_t)(bn + srow) * K + k0 + scol;
    gload16(gb,        dst + B_OFF + (w << 10));
    if (SPLIT_IN) {
      const f16* gal = Alo + (size_t)(bm + srow) * K + k0 + scol;
      gload16(gal,        dst + ALO_OFF + (w << 10));
      gload16(gal + 64*K, dst + ALO_OFF + 4096 + (w << 10));
      const f16* gbl = Blo + (size_t)(bn + srow) * K + k0 + scol;
      gload16(gbl,        dst + BLO_OFF + (w << 10));
    }
  };

  const int nkt = K >> 5;
  stage(0);

  for (int kt = 0; kt < nkt; kt++) {
    if (kt + 1 < nkt) {
      stage(kt + 1);
      if constexpr (SPLIT_IN) asm volatile("s_waitcnt vmcnt(6)" ::: "memory");
      else                    asm volatile("s_waitcnt vmcnt(3)" ::: "memory");
    } else {
      asm volatile("s_waitcnt vmcnt(0)" ::: "memory");
    }
    __builtin_amdgcn_s_barrier();

    const char* buf = smem + (kt & 1) * STRIDE;
    const int ar = (l & 15);
    const int ak = (l >> 4) * 16;
    f16x8 a_hi[4], a_lo[4];
#pragma unroll
    for (int mi = 0; mi < 4; mi++) {
      a_hi[mi] = *(const f16x8*)(buf + (size_t)(wr + mi*16 + ar) * 64 + ak);
      if (SPLIT_IN)
        a_lo[mi] = *(const f16x8*)(buf + ALO_OFF + (size_t)(wr + mi*16 + ar) * 64 + ak);
    }
#pragma unroll
    for (int ni = 0; ni < 2; ni++) {
      f16x8 b_hi = *(const f16x8*)(buf + B_OFF + (size_t)(wc + ni*16 + ar) * 64 + ak);
      f16x8 b_lo = {};
      if (SPLIT_IN)
        b_lo = *(const f16x8*)(buf + BLO_OFF + (size_t)(wc + ni*16 + ar) * 64 + ak);
#pragma unroll
      for (int mi = 0; mi < 4; mi++) {
        acc[mi][ni] = MFMA16(a_hi[mi], b_hi, acc[mi][ni], 0, 0, 0);
        if (SPLIT_IN) {
          acc[mi][ni] = MFMA16(a_hi[mi], b_lo, acc[mi][ni], 0, 0, 0);
          acc[mi][ni] = MFMA16(a_lo[mi], b_hi, acc[mi][ni], 0, 0, 0);
        }
      }
    }
    __builtin_amdgcn_s_barrier();
  }

  const int crow0 = bm + wr + (l >> 4) * 4;
  const int ccol0 = bn + wc + (l & 15);
#pragma unroll
  for (int mi = 0; mi < 4; mi++) {
#pragma unroll
    for (int ni = 0; ni < 2; ni++) {
#pragma unroll
      for (int j = 0; j < 4; j++) {
        size_t idx = (size_t)(crow0 + mi*16 + j) * N + (ccol0 + ni*16);
        float v = acc[mi][ni][j];
        if (F32_OUT) {
          Cf[idx] = v;
        } else {
          f16 h = (f16)v;
          Chi[idx] = h;
          if (SPLIT_OUT) Clo[idx] = (f16)(v - (float)h);
        }
      }
    }
  }
}

// ---------------- flash attention v4 (causal, transposed scores) ----------------
// QBLK=64 (4 waves x 16 q), KVBLK=32, 2-deep pipelined staging (vmcnt(3)).
// S^T = mfma(K, Q): lane owns q = qw + (l&15); kv = ni*16 + 4*(l>>4) + j in regs.
// Softmax: in-lane reduce (7 ops) + 2 shfl_xor; scalar m/l per lane.
// P^T B-fragment built in-register: cvt_pkrtz packs + 8 ds_bpermute + 4 selects.
// O accumulated transposed via mfma(VT_frag, PT_frag); 8B stores in epilogue.
__global__ __launch_bounds__(256, 4)
void attn_kernel(const f16* __restrict__ Qhi, const f16* __restrict__ Qlo,
                 const f16* __restrict__ Khi, const f16* __restrict__ Klo,
                 const f16* __restrict__ VT, f16* __restrict__ Out)
{
  __shared__ __align__(16) char smem[24576];   // 2 x (Khi 4K | Klo 4K | VT 4K)

  const int tid = threadIdx.x, w = tid >> 6, l = tid & 63;
  const int g = l >> 4, q4 = l & 15;
  const int flat = blockIdx.x;
  const int xcd = flat & 7, slot = flat >> 3;
  const int r4 = slot >> 5, ii = slot & 31;
  const int bh = xcd * 4 + r4;                 // XCD keeps 4 heads resident
  const int qx = (r4 & 1) ? (31 - ii) : ii;    // per-CU qx pairing {c,31-c}
  const int b = bh >> 4, h = bh & 15;
  const int q0 = qx * 64;
  const int qw = q0 + w * 16;
  const int bS = b * SEQ;
  const size_t hoff = (size_t)h * 64;
  const int niter = 2 * qx + 2;

  // persistent Q fragments (pre-scaled by 0.125*log2e via weight split)
  f16x8 qh[2], ql[2];
#pragma unroll
  for (int ks = 0; ks < 2; ks++) {
    const size_t base = (size_t)(bS + qw + q4) * D_MODEL + hoff + ks * 32 + g * 8;
    qh[ks] = *(const f16x8*)(Qhi + base);
    ql[ks] = *(const f16x8*)(Qlo + base);
  }

  f32x4 o[4] = {};
  float m_run = -INFINITY, l_run = 0.f;

  const int k_src_off = 8 * ((l & 7) ^ (l >> 3));
  const int v_src_off = 8 * ((l & 3) ^ ((l >> 3) & 3));

  auto stage = [&](int t) {
    char* dst = smem + (t & 1) * 12288;
    const int kv0 = t * 32;
    const size_t krow = (size_t)(bS + kv0 + w * 8 + (l >> 3)) * D_MODEL + hoff + k_src_off;
    gload16(Khi + krow, dst + w * 1024);
    gload16(Klo + krow, dst + 4096 + w * 1024);
    const size_t vrow = (hoff + w * 16 + (l >> 2)) * (size_t)NROWS + bS + kv0 + v_src_off;
    gload16(VT + vrow, dst + 8192 + w * 1024);
  };

  // P^T redistribution constants
  const int idx_lo = (q4 + 32 * (g & 1)) * 4;
  const int idx_hi = idx_lo + 64;
  const bool upper = (l >= 32);   // ni = g>>1

  stage(0);

  for (int t = 0; t < niter; t++) {
    if (t + 1 < niter) {
      stage(t + 1);
      asm volatile("s_waitcnt vmcnt(3)" ::: "memory");
    } else {
      asm volatile("s_waitcnt vmcnt(0)" ::: "memory");
    }
    __builtin_amdgcn_s_barrier();

    const int kv0 = t * 32;
    if (kv0 <= qw + 15) {
      const char* bufK = smem + (t & 1) * 12288;

      // ---- S^T = K Q^T (split fp16, exp2 domain) ----
      f32x4 s[2] = {};
#pragma unroll
      for (int ni = 0; ni < 2; ni++) {
        const int row = ni * 16 + q4;
#pragma unroll
        for (int ks = 0; ks < 2; ks++) {
          const int boff = row * 128 + 16 * ((ks * 4 + g) ^ (row & 7));
          f16x8 kh8 = *(const f16x8*)(bufK + boff);
          f16x8 kl8 = *(const f16x8*)(bufK + 4096 + boff);
          s[ni] = MFMA16(kh8, qh[ks], s[ni], 0, 0, 0);
          s[ni] = MFMA16(kh8, ql[ks], s[ni], 0, 0, 0);
          s[ni] = MFMA16(kl8, qh[ks], s[ni], 0, 0, 0);
        }
      }

      // ---- causal mask + row max (in-lane + 2 shfl) ----
      const bool need_mask = (kv0 + 31) > qw;
      const int q_abs = qw + q4;
      float p[2][4];
      float pm = -INFINITY;
#pragma unroll
      for (int ni = 0; ni < 2; ni++)
#pragma unroll
        for (int j = 0; j < 4; j++) {
          float v = s[ni][j];
          if (need_mask && (kv0 + ni*16 + 4*g + j) > q_abs) v = -INFINITY;
          p[ni][j] = v;
          pm = fmaxf(pm, v);
        }
      pm = fmaxf(pm, __shfl_xor(pm, 16));
      pm = fmaxf(pm, __shfl_xor(pm, 32));

      // ---- online softmax (exp2, scalar state per lane) ----
      const float mn = fmaxf(m_run, pm);
      const float sc = __builtin_amdgcn_exp2f(m_run - mn);
      m_run = mn;
      float ps = 0.f;
#pragma unroll
      for (int ni = 0; ni < 2; ni++)
#pragma unroll
        for (int j = 0; j < 4; j++) {
          const float e = __builtin_amdgcn_exp2f(p[ni][j] - mn);
          p[ni][j] = e;
          ps += e;
        }
      ps += __shfl_xor(ps, 16);
      ps += __shfl_xor(ps, 32);
      l_run = l_run * sc + ps;
#pragma unroll
      for (int nd = 0; nd < 4; nd++)
#pragma unroll
        for (int j = 0; j < 4; j++) o[nd][j] *= sc;

      // ---- build P^T B-fragment in-register ----
      // packs[p]: f16 pair at kv = 16*(p>>1) + 4*g + 2*(p&1) + {0,1}
      const int pk0 = pkh2(p[0][0], p[0][1]);
      const int pk1 = pkh2(p[0][2], p[0][3]);
      const int pk2 = pkh2(p[1][0], p[1][1]);
      const int pk3 = pkh2(p[1][2], p[1][3]);
      // target chunk t: pack[2*(g>>1)+(t&1)] from lane (q4, 2*(g&1)+(t>>1))
      const int b0l = __builtin_amdgcn_ds_bpermute(idx_lo, pk0);
      const int b2l = __builtin_amdgcn_ds_bpermute(idx_lo, pk2);
      const int b1l = __builtin_amdgcn_ds_bpermute(idx_lo, pk1);
      const int b3l = __builtin_amdgcn_ds_bpermute(idx_lo, pk3);
      const int b0h = __builtin_amdgcn_ds_bpermute(idx_hi, pk0);
      const int b2h = __builtin_amdgcn_ds_bpermute(idx_hi, pk2);
      const int b1h = __builtin_amdgcn_ds_bpermute(idx_hi, pk1);
      const int b3h = __builtin_amdgcn_ds_bpermute(idx_hi, pk3);
      union { int u[4]; f16x8 v; } pu;
      pu.u[0] = upper ? b2l : b0l;
      pu.u[1] = upper ? b3l : b1l;
      pu.u[2] = upper ? b2h : b0h;
      pu.u[3] = upper ? b3h : b1h;
      const f16x8 pa = pu.v;

      // ---- O^T += V^T P^T ----
#pragma unroll
      for (int nd = 0; nd < 4; nd++) {
        const int d = nd * 16 + q4;
        f16x8 bv = *(const f16x8*)(bufK + 8192 + d * 64 + 16 * (g ^ ((d >> 1) & 3)));
        o[nd] = MFMA16(bv, pa, o[nd], 0, 0, 0);
      }
    }
    __builtin_amdgcn_s_barrier();
  }

  // ---- epilogue: O^T[d][q] -> Out[q][d], 8B stores ----
  const float inv = 1.0f / l_run;
  const size_t rowb = (size_t)(bS + qw + q4) * D_MODEL + hoff;
#pragma unroll
  for (int nd = 0; nd < 4; nd++) {
    f16x4 v;
#pragma unroll
    for (int j = 0; j < 4; j++) v[j] = (f16)(o[nd][j] * inv);
    *reinterpret_cast<f16x4*>(Out + rowb + nd * 16 + 4 * g) = v;
  }
}

// ---------------- launcher ----------------
extern "C" void kernel_launch(void* const* d_in, const int* in_sizes, int n_in,
                              void* d_out, int out_size, void* d_ws, size_t ws_size,
                              hipStream_t stream) {
  const float* x  = (const float*)d_in[0];
  const float* pq = (const float*)d_in[1];
  const float* pk = (const float*)d_in[2];
  const float* pv = (const float*)d_in[3];
  const float* po = (const float*)d_in[4];
  float* out = (float*)d_out;

  char* ws = (char*)d_ws;
  size_t off = 0;
  auto alloc = [&](size_t elems) {
    f16* p = (f16*)(ws + off);
    off += ((elems * 2 + 255) & ~(size_t)255);
    return p;
  };
  f16* x_hi  = alloc((size_t)NROWS * D_MODEL);
  f16* x_lo  = alloc((size_t)NROWS * D_MODEL);
  f16* wq_hi = alloc((size_t)D_MODEL * D_MODEL);
  f16* wq_lo = alloc((size_t)D_MODEL * D_MODEL);
  f16* wk_hi = alloc((size_t)D_MODEL * D_MODEL);
  f16* wk_lo = alloc((size_t)D_MODEL * D_MODEL);
  f16* wv_h  = alloc((size_t)D_MODEL * D_MODEL);
  f16* wo_h  = alloc((size_t)D_MODEL * D_MODEL);
  f16* q_hi  = alloc((size_t)NROWS * D_MODEL);
  f16* q_lo  = alloc((size_t)NROWS * D_MODEL);
  f16* k_hi  = alloc((size_t)NROWS * D_MODEL);
  f16* k_lo  = alloc((size_t)NROWS * D_MODEL);
  f16* vt    = alloc((size_t)NROWS * D_MODEL);   // VT[m][b*SEQ+s]
  f16* ao    = alloc((size_t)NROWS * D_MODEL);

  const int n4x = NROWS * D_MODEL / 4;
  const int n4w = D_MODEL * D_MODEL / 4;
  const float qscale = 0.125f * 1.44269504088896f;
  split4_kernel<<<n4x/256, 256, 0, stream>>>(x,  x_hi,  x_lo,  n4x, 1.0f);
  split4_kernel<<<n4w/256, 256, 0, stream>>>(pq, wq_hi, wq_lo, n4w, qscale);
  split4_kernel<<<n4w/256, 256, 0, stream>>>(pk, wk_hi, wk_lo, n4w, 1.0f);
  cvt4_kernel  <<<n4w/256, 256, 0, stream>>>(pv, wv_h, n4w);
  cvt4_kernel  <<<n4w/256, 256, 0, stream>>>(po, wo_h, n4w);

  dim3 gg(D_MODEL/64, NROWS/128);  // (16, 32)
  gemm_nt<true,  true,  false, false><<<gg, 256, 0, stream>>>(x_hi, x_lo, wq_hi, wq_lo, q_hi, q_lo, nullptr, NROWS, D_MODEL, D_MODEL);
  gemm_nt<true,  true,  false, false><<<gg, 256, 0, stream>>>(x_hi, x_lo, wk_hi, wk_lo, k_hi, k_lo, nullptr, NROWS, D_MODEL, D_MODEL);
  // V projection with transposed output: VT[m][n] = sum_k wv[m][k] x[n][k]
  dim3 gv(NROWS/64, D_MODEL/128);  // (64, 8) -- col-chunked XCD swizzle
  gemm_nt<false, false, false, true><<<gv, 256, 0, stream>>>(wv_h, nullptr, x_hi, nullptr, vt, nullptr, nullptr, D_MODEL, NROWS, D_MODEL);

  attn_kernel<<<dim3(1024), 256, 0, stream>>>(q_hi, q_lo, k_hi, k_lo, vt, ao);

  gemm_nt<false, false, true, false><<<gg, 256, 0, stream>>>(ao, nullptr, wo_h, nullptr, nullptr, nullptr, out, NROWS, D_MODEL, D_MODEL);
}

// Round 6
// 178.545 us; speedup vs baseline: 2.2714x; 1.0983x over previous
//
#include <hip/hip_runtime.h>
#include <stdint.h>

#define D_MODEL 1024
#define SEQ     2048
#define NHEAD   16
#define BATCH   2
#define NROWS   (BATCH*SEQ)   // 4096

typedef _Float16 f16;
typedef _Float16 f16x8 __attribute__((ext_vector_type(8)));
typedef _Float16 f16x4 __attribute__((ext_vector_type(4)));
typedef __fp16   h16x2 __attribute__((ext_vector_type(2)));
typedef float    f32x4 __attribute__((ext_vector_type(4)));

#define MFMA16 __builtin_amdgcn_mfma_f32_16x16x32_f16

__device__ __forceinline__ void gload16(const void* g, void* l) {
  __builtin_amdgcn_global_load_lds(
      (const __attribute__((address_space(1))) void*)g,
      (__attribute__((address_space(3))) void*)l, 16, 0, 0);
}

__device__ __forceinline__ int pkh2(float a, float b) {
  union { h16x2 h; int i; } u;
  u.h = __builtin_amdgcn_cvt_pkrtz(a, b);
  return u.i;
}

// ---------------- convert / split kernels ----------------
__global__ void split4_kernel(const float* __restrict__ in, f16* __restrict__ hi,
                              f16* __restrict__ lo, int n4, float scale) {
  int i = blockIdx.x * blockDim.x + threadIdx.x;
  if (i >= n4) return;
  float4 v = reinterpret_cast<const float4*>(in)[i];
  v.x *= scale; v.y *= scale; v.z *= scale; v.w *= scale;
  f16x4 h, l4;
  h[0] = (f16)v.x; h[1] = (f16)v.y; h[2] = (f16)v.z; h[3] = (f16)v.w;
  l4[0] = (f16)(v.x - (float)h[0]);
  l4[1] = (f16)(v.y - (float)h[1]);
  l4[2] = (f16)(v.z - (float)h[2]);
  l4[3] = (f16)(v.w - (float)h[3]);
  *reinterpret_cast<f16x4*>(hi + 4*(size_t)i) = h;
  *reinterpret_cast<f16x4*>(lo + 4*(size_t)i) = l4;
}

// fused weight prep: wq split (scaled), wk split, wv cvt, wo cvt — one pass
__global__ void prep_w_kernel(const float* __restrict__ pq, const float* __restrict__ pk,
                              const float* __restrict__ pv, const float* __restrict__ po,
                              f16* __restrict__ wq_hi, f16* __restrict__ wq_lo,
                              f16* __restrict__ wk_hi, f16* __restrict__ wk_lo,
                              f16* __restrict__ wv_h,  f16* __restrict__ wo_h,
                              int n4, float qscale) {
  int i = blockIdx.x * blockDim.x + threadIdx.x;
  if (i >= n4) return;
  {
    float4 v = reinterpret_cast<const float4*>(pq)[i];
    v.x *= qscale; v.y *= qscale; v.z *= qscale; v.w *= qscale;
    f16x4 h, l4;
    h[0] = (f16)v.x; h[1] = (f16)v.y; h[2] = (f16)v.z; h[3] = (f16)v.w;
    l4[0] = (f16)(v.x - (float)h[0]); l4[1] = (f16)(v.y - (float)h[1]);
    l4[2] = (f16)(v.z - (float)h[2]); l4[3] = (f16)(v.w - (float)h[3]);
    *reinterpret_cast<f16x4*>(wq_hi + 4*(size_t)i) = h;
    *reinterpret_cast<f16x4*>(wq_lo + 4*(size_t)i) = l4;
  }
  {
    float4 v = reinterpret_cast<const float4*>(pk)[i];
    f16x4 h, l4;
    h[0] = (f16)v.x; h[1] = (f16)v.y; h[2] = (f16)v.z; h[3] = (f16)v.w;
    l4[0] = (f16)(v.x - (float)h[0]); l4[1] = (f16)(v.y - (float)h[1]);
    l4[2] = (f16)(v.z - (float)h[2]); l4[3] = (f16)(v.w - (float)h[3]);
    *reinterpret_cast<f16x4*>(wk_hi + 4*(size_t)i) = h;
    *reinterpret_cast<f16x4*>(wk_lo + 4*(size_t)i) = l4;
  }
  {
    float4 v = reinterpret_cast<const float4*>(pv)[i];
    f16x4 h;
    h[0] = (f16)v.x; h[1] = (f16)v.y; h[2] = (f16)v.z; h[3] = (f16)v.w;
    *reinterpret_cast<f16x4*>(wv_h + 4*(size_t)i) = h;
  }
  {
    float4 v = reinterpret_cast<const float4*>(po)[i];
    f16x4 h;
    h[0] = (f16)v.x; h[1] = (f16)v.y; h[2] = (f16)v.z; h[3] = (f16)v.w;
    *reinterpret_cast<f16x4*>(wo_h + 4*(size_t)i) = h;
  }
}

// ---------------- GEMM: C[M,N] = A[M,K] · B[N,K]^T  (NT) ----------------
// BM=128, BN=64, BK=32, double-buffered, counted vmcnt.
// LDS rows are 64B (4 x 16B chunks): XOR swizzle chunk c -> c ^ ((row>>1)&3)
// (source-side pre-swizzle; reads apply the same XOR) to kill the 8-way
// quarter-wave bank conflict of column-chunk reads.
template<bool SPLIT_IN, bool SPLIT_OUT, bool F32_OUT, bool COLCHUNK>
__global__ __launch_bounds__(256, 2)
void gemm_nt(const f16* __restrict__ Ahi, const f16* __restrict__ Alo,
             const f16* __restrict__ Bhi, const f16* __restrict__ Blo,
             f16* __restrict__ Chi, f16* __restrict__ Clo, float* __restrict__ Cf,
             int M, int N, int K)
{
  constexpr int ALO_OFF = 8192;
  constexpr int B_OFF   = SPLIT_IN ? 16384 : 8192;
  constexpr int BLO_OFF = 20480;
  constexpr int STRIDE  = SPLIT_IN ? 24576 : 12288;
  __shared__ __align__(16) char smem[2 * STRIDE];

  const int tid = threadIdx.x;
  const int w = tid >> 6, l = tid & 63;
  const int wr = (w >> 1) * 64;
  const int wc = (w & 1) * 32;

  const int gx = gridDim.x, gy = gridDim.y;
  const int nwg = gx * gy;
  const int flat = blockIdx.y * gx + blockIdx.x;
  const int swz = (flat & 7) * (nwg >> 3) + (flat >> 3);
  const int bxn = COLCHUNK ? (swz / gy) : (swz % gx);
  const int byn = COLCHUNK ? (swz % gy) : (swz / gx);
  const int bm = byn * 128, bn = bxn * 64;

  f32x4 acc[4][2] = {};

  const int srow = tid >> 2;
  const int schunk = 8 * (((tid & 3) ^ ((srow >> 1) & 3)));  // swizzled source chunk (f16 elems)

  auto stage = [&](int kt) {
    char* dst = smem + (kt & 1) * STRIDE;
    const int k0 = kt * 32;
    const f16* ga = Ahi + (size_t)(bm + srow) * K + k0 + schunk;
    gload16(ga,        dst + (w << 10));
    gload16(ga + 64*K, dst + 4096 + (w << 10));
    const f16* gb = Bhi + (size_t)(bn + srow) * K + k0 + schunk;
    gload16(gb,        dst + B_OFF + (w << 10));
    if (SPLIT_IN) {
      const f16* gal = Alo + (size_t)(bm + srow) * K + k0 + schunk;
      gload16(gal,        dst + ALO_OFF + (w << 10));
      gload16(gal + 64*K, dst + ALO_OFF + 4096 + (w << 10));
      const f16* gbl = Blo + (size_t)(bn + srow) * K + k0 + schunk;
      gload16(gbl,        dst + BLO_OFF + (w << 10));
    }
  };

  const int nkt = K >> 5;
  stage(0);

  for (int kt = 0; kt < nkt; kt++) {
    if (kt + 1 < nkt) {
      stage(kt + 1);
      if constexpr (SPLIT_IN) asm volatile("s_waitcnt vmcnt(6)" ::: "memory");
      else                    asm volatile("s_waitcnt vmcnt(3)" ::: "memory");
    } else {
      asm volatile("s_waitcnt vmcnt(0)" ::: "memory");
    }
    __builtin_amdgcn_s_barrier();

    const char* buf = smem + (kt & 1) * STRIDE;
    const int ar = (l & 15);
    const int ak = 16 * ((l >> 4) ^ ((ar >> 1) & 3));   // swizzled chunk read
    f16x8 a_hi[4], a_lo[4];
#pragma unroll
    for (int mi = 0; mi < 4; mi++) {
      a_hi[mi] = *(const f16x8*)(buf + (size_t)(wr + mi*16 + ar) * 64 + ak);
      if (SPLIT_IN)
        a_lo[mi] = *(const f16x8*)(buf + ALO_OFF + (size_t)(wr + mi*16 + ar) * 64 + ak);
    }
    __builtin_amdgcn_s_setprio(1);
#pragma unroll
    for (int ni = 0; ni < 2; ni++) {
      f16x8 b_hi = *(const f16x8*)(buf + B_OFF + (size_t)(wc + ni*16 + ar) * 64 + ak);
      f16x8 b_lo = {};
      if (SPLIT_IN)
        b_lo = *(const f16x8*)(buf + BLO_OFF + (size_t)(wc + ni*16 + ar) * 64 + ak);
#pragma unroll
      for (int mi = 0; mi < 4; mi++) {
        acc[mi][ni] = MFMA16(a_hi[mi], b_hi, acc[mi][ni], 0, 0, 0);
        if (SPLIT_IN) {
          acc[mi][ni] = MFMA16(a_hi[mi], b_lo, acc[mi][ni], 0, 0, 0);
          acc[mi][ni] = MFMA16(a_lo[mi], b_hi, acc[mi][ni], 0, 0, 0);
        }
      }
    }
    __builtin_amdgcn_s_setprio(0);
    __builtin_amdgcn_s_barrier();
  }

  const int crow0 = bm + wr + (l >> 4) * 4;
  const int ccol0 = bn + wc + (l & 15);
#pragma unroll
  for (int mi = 0; mi < 4; mi++) {
#pragma unroll
    for (int ni = 0; ni < 2; ni++) {
#pragma unroll
      for (int j = 0; j < 4; j++) {
        size_t idx = (size_t)(crow0 + mi*16 + j) * N + (ccol0 + ni*16);
        float v = acc[mi][ni][j];
        if (F32_OUT) {
          Cf[idx] = v;
        } else {
          f16 h = (f16)v;
          Chi[idx] = h;
          if (SPLIT_OUT) Clo[idx] = (f16)(v - (float)h);
        }
      }
    }
  }
}

// ---------------- flash attention v5 (causal, transposed scores) ----------------
// QBLK=128 (8 waves x 16 q), KVBLK=64, 512 blocks x 512 threads (16 waves/CU).
// K(hi/lo)+VT staged once per block, shared by 8 waves; 2-deep pipeline vmcnt(3).
// S^T = mfma(K, Q); in-lane softmax (scalar m/l per lane, lane owns q = l&15).
// P^T built in-register per 32-kv half (cvt_pkrtz + 8 bpermute + selects).
// Balanced pairing: slot s and s+32 (same CU position) get qx and 15-qx.
__global__ __launch_bounds__(512, 4)
void attn_kernel(const f16* __restrict__ Qhi, const f16* __restrict__ Qlo,
                 const f16* __restrict__ Khi, const f16* __restrict__ Klo,
                 const f16* __restrict__ VT, f16* __restrict__ Out)
{
  __shared__ __align__(16) char smem[49152];   // 2 x (Khi 8K | Klo 8K | VT 8K)

  const int tid = threadIdx.x, w = tid >> 6, l = tid & 63;
  const int g = l >> 4, q4 = l & 15;
  const int flat = blockIdx.x;
  const int xcd = flat & 7, slot = flat >> 3;
  const int r4 = slot >> 4;                    // 0..3 -> head group on this XCD
  const int ii = slot & 15;
  const int bh = xcd * 4 + r4;                 // XCD keeps 4 heads resident
  const int qx = ((slot >> 5) & 1) ? (15 - ii) : ii;  // s and s+32 balanced
  const int b = bh >> 4, h = bh & 15;
  const int q0 = qx * 128;
  const int qw = q0 + w * 16;
  const int bS = b * SEQ;
  const size_t hoff = (size_t)h * 64;
  const int niter = 2 * qx + 2;

  // persistent Q fragments (pre-scaled by 0.125*log2e via weight split)
  f16x8 qh[2], ql[2];
#pragma unroll
  for (int ks = 0; ks < 2; ks++) {
    const size_t base = (size_t)(bS + qw + q4) * D_MODEL + hoff + ks * 32 + g * 8;
    qh[ks] = *(const f16x8*)(Qhi + base);
    ql[ks] = *(const f16x8*)(Qlo + base);
  }

  f32x4 o[4] = {};
  float m_run = -INFINITY, l_run = 0.f;

  const int src_off = 8 * ((l & 7) ^ (l >> 3));   // chunk ^ (row&7), in f16 elems
  const int rowloc = w * 8 + (l >> 3);            // tile-local row staged by this lane

  auto stage = [&](int t) {
    char* dst = smem + (t & 1) * 24576;
    const int kv0 = t * 64;
    const size_t krow = (size_t)(bS + kv0 + rowloc) * D_MODEL + hoff + src_off;
    gload16(Khi + krow, dst + (w << 10));
    gload16(Klo + krow, dst + 8192 + (w << 10));
    const size_t vrow = (hoff + rowloc) * (size_t)NROWS + bS + kv0 + src_off;
    gload16(VT + vrow, dst + 16384 + (w << 10));
  };

  // P^T redistribution constants (per 32-kv half)
  const int idx_lo = (q4 + 32 * (g & 1)) * 4;
  const int idx_hi = idx_lo + 64;
  const bool upper = (l >= 32);

  stage(0);

  for (int t = 0; t < niter; t++) {
    if (t + 1 < niter) {
      stage(t + 1);
      asm volatile("s_waitcnt vmcnt(3)" ::: "memory");
    } else {
      asm volatile("s_waitcnt vmcnt(0)" ::: "memory");
    }
    __builtin_amdgcn_s_barrier();

    const int kv0 = t * 64;
    if (kv0 <= qw + 15) {
      const char* buf = smem + (t & 1) * 24576;

      // ---- S^T = K Q^T (split fp16, exp2 domain) ----
      f32x4 s[4] = {};
      __builtin_amdgcn_s_setprio(1);
#pragma unroll
      for (int ni = 0; ni < 4; ni++) {
        const int row = ni * 16 + q4;
#pragma unroll
        for (int ks = 0; ks < 2; ks++) {
          const int boff = row * 128 + 16 * ((ks * 4 + g) ^ (row & 7));
          f16x8 kh8 = *(const f16x8*)(buf + boff);
          f16x8 kl8 = *(const f16x8*)(buf + 8192 + boff);
          s[ni] = MFMA16(kh8, qh[ks], s[ni], 0, 0, 0);
          s[ni] = MFMA16(kh8, ql[ks], s[ni], 0, 0, 0);
          s[ni] = MFMA16(kl8, qh[ks], s[ni], 0, 0, 0);
        }
      }
      __builtin_amdgcn_s_setprio(0);

      // ---- causal mask + row max (in-lane + 2 shfl) ----
      const bool need_mask = (kv0 + 63) > qw;
      const int q_abs = qw + q4;
      float p[4][4];
      float pm = -INFINITY;
#pragma unroll
      for (int ni = 0; ni < 4; ni++)
#pragma unroll
        for (int j = 0; j < 4; j++) {
          float v = s[ni][j];
          if (need_mask && (kv0 + ni*16 + 4*g + j) > q_abs) v = -INFINITY;
          p[ni][j] = v;
          pm = fmaxf(pm, v);
        }
      pm = fmaxf(pm, __shfl_xor(pm, 16));
      pm = fmaxf(pm, __shfl_xor(pm, 32));

      // ---- online softmax (exp2, scalar state per lane) ----
      const float mn = fmaxf(m_run, pm);
      const float sc = __builtin_amdgcn_exp2f(m_run - mn);
      m_run = mn;
      float ps = 0.f;
#pragma unroll
      for (int ni = 0; ni < 4; ni++)
#pragma unroll
        for (int j = 0; j < 4; j++) {
          const float e = __builtin_amdgcn_exp2f(p[ni][j] - mn);
          p[ni][j] = e;
          ps += e;
        }
      ps += __shfl_xor(ps, 16);
      ps += __shfl_xor(ps, 32);
      l_run = l_run * sc + ps;
#pragma unroll
      for (int nd = 0; nd < 4; nd++)
#pragma unroll
        for (int j = 0; j < 4; j++) o[nd][j] *= sc;

      // ---- build P^T B-fragments (one per 32-kv half) ----
      f16x8 pa[2];
#pragma unroll
      for (int h2 = 0; h2 < 2; h2++) {
        const int pk0 = pkh2(p[2*h2][0],   p[2*h2][1]);
        const int pk1 = pkh2(p[2*h2][2],   p[2*h2][3]);
        const int pk2 = pkh2(p[2*h2+1][0], p[2*h2+1][1]);
        const int pk3 = pkh2(p[2*h2+1][2], p[2*h2+1][3]);
        const int b0l = __builtin_amdgcn_ds_bpermute(idx_lo, pk0);
        const int b2l = __builtin_amdgcn_ds_bpermute(idx_lo, pk2);
        const int b1l = __builtin_amdgcn_ds_bpermute(idx_lo, pk1);
        const int b3l = __builtin_amdgcn_ds_bpermute(idx_lo, pk3);
        const int b0h = __builtin_amdgcn_ds_bpermute(idx_hi, pk0);
        const int b2h = __builtin_amdgcn_ds_bpermute(idx_hi, pk2);
        const int b1h = __builtin_amdgcn_ds_bpermute(idx_hi, pk1);
        const int b3h = __builtin_amdgcn_ds_bpermute(idx_hi, pk3);
        union { int u[4]; f16x8 v; } pu;
        pu.u[0] = upper ? b2l : b0l;
        pu.u[1] = upper ? b3l : b1l;
        pu.u[2] = upper ? b2h : b0h;
        pu.u[3] = upper ? b3h : b1h;
        pa[h2] = pu.v;
      }

      // ---- O^T += V^T P^T ----
      __builtin_amdgcn_s_setprio(1);
#pragma unroll
      for (int nd = 0; nd < 4; nd++) {
        const int d = nd * 16 + q4;
#pragma unroll
        for (int h2 = 0; h2 < 2; h2++) {
          f16x8 bv = *(const f16x8*)(buf + 16384 + d * 128 + 16 * ((h2 * 4 + g) ^ (d & 7)));
          o[nd] = MFMA16(bv, pa[h2], o[nd], 0, 0, 0);
        }
      }
      __builtin_amdgcn_s_setprio(0);
    }
    __builtin_amdgcn_s_barrier();
  }

  // ---- epilogue: O^T[d][q] -> Out[q][d], 8B stores ----
  const float inv = 1.0f / l_run;
  const size_t rowb = (size_t)(bS + qw + q4) * D_MODEL + hoff;
#pragma unroll
  for (int nd = 0; nd < 4; nd++) {
    f16x4 v;
#pragma unroll
    for (int j = 0; j < 4; j++) v[j] = (f16)(o[nd][j] * inv);
    *reinterpret_cast<f16x4*>(Out + rowb + nd * 16 + 4 * g) = v;
  }
}

// ---------------- launcher ----------------
extern "C" void kernel_launch(void* const* d_in, const int* in_sizes, int n_in,
                              void* d_out, int out_size, void* d_ws, size_t ws_size,
                              hipStream_t stream) {
  const float* x  = (const float*)d_in[0];
  const float* pq = (const float*)d_in[1];
  const float* pk = (const float*)d_in[2];
  const float* pv = (const float*)d_in[3];
  const float* po = (const float*)d_in[4];
  float* out = (float*)d_out;

  char* ws = (char*)d_ws;
  size_t off = 0;
  auto alloc = [&](size_t elems) {
    f16* p = (f16*)(ws + off);
    off += ((elems * 2 + 255) & ~(size_t)255);
    return p;
  };
  f16* x_hi  = alloc((size_t)NROWS * D_MODEL);
  f16* x_lo  = alloc((size_t)NROWS * D_MODEL);
  f16* wq_hi = alloc((size_t)D_MODEL * D_MODEL);
  f16* wq_lo = alloc((size_t)D_MODEL * D_MODEL);
  f16* wk_hi = alloc((size_t)D_MODEL * D_MODEL);
  f16* wk_lo = alloc((size_t)D_MODEL * D_MODEL);
  f16* wv_h  = alloc((size_t)D_MODEL * D_MODEL);
  f16* wo_h  = alloc((size_t)D_MODEL * D_MODEL);
  f16* q_hi  = alloc((size_t)NROWS * D_MODEL);
  f16* q_lo  = alloc((size_t)NROWS * D_MODEL);
  f16* k_hi  = alloc((size_t)NROWS * D_MODEL);
  f16* k_lo  = alloc((size_t)NROWS * D_MODEL);
  f16* vt    = alloc((size_t)NROWS * D_MODEL);   // VT[m][b*SEQ+s]
  f16* ao    = alloc((size_t)NROWS * D_MODEL);

  const int n4x = NROWS * D_MODEL / 4;
  const int n4w = D_MODEL * D_MODEL / 4;
  const float qscale = 0.125f * 1.44269504088896f;
  split4_kernel<<<n4x/256, 256, 0, stream>>>(x, x_hi, x_lo, n4x, 1.0f);
  prep_w_kernel<<<n4w/256, 256, 0, stream>>>(pq, pk, pv, po,
                                             wq_hi, wq_lo, wk_hi, wk_lo, wv_h, wo_h,
                                             n4w, qscale);

  dim3 gg(D_MODEL/64, NROWS/128);  // (16, 32)
  gemm_nt<true,  true,  false, false><<<gg, 256, 0, stream>>>(x_hi, x_lo, wq_hi, wq_lo, q_hi, q_lo, nullptr, NROWS, D_MODEL, D_MODEL);
  gemm_nt<true,  true,  false, false><<<gg, 256, 0, stream>>>(x_hi, x_lo, wk_hi, wk_lo, k_hi, k_lo, nullptr, NROWS, D_MODEL, D_MODEL);
  // V projection with transposed output: VT[m][n] = sum_k wv[m][k] x[n][k]
  dim3 gv(NROWS/64, D_MODEL/128);  // (64, 8) -- col-chunked XCD swizzle
  gemm_nt<false, false, false, true><<<gv, 256, 0, stream>>>(wv_h, nullptr, x_hi, nullptr, vt, nullptr, nullptr, D_MODEL, NROWS, D_MODEL);

  attn_kernel<<<dim3(512), 512, 0, stream>>>(q_hi, q_lo, k_hi, k_lo, vt, ao);

  gemm_nt<false, false, true, false><<<gg, 256, 0, stream>>>(ao, nullptr, wo_h, nullptr, nullptr, nullptr, out, NROWS, D_MODEL, D_MODEL);
}